// Round 4
// baseline (183.055 us; speedup 1.0000x reference)
//
#include <hip/hip_runtime.h>
#include <hip/hip_bf16.h>

#define N 8192
#define F 256
#define KSPLIT 4
#define JB (N / KSPLIT)   // 2048 cols per k3 block
#define NIT (JB / 64)     // 32 j-tiles

using s16x8 = __attribute__((ext_vector_type(8))) short;
using f32x4 = __attribute__((ext_vector_type(4))) float;

static __device__ __forceinline__ unsigned short f2bf(float f) {
  unsigned int u = __float_as_uint(f);
  unsigned int r = u + 0x7fffu + ((u >> 16) & 1u);   // RNE
  return (unsigned short)(r >> 16);
}
static __device__ __forceinline__ float bf2f(unsigned short u) {
  return __uint_as_float(((unsigned int)u) << 16);
}

// ---------------- k_mask: adj -> byte-per-4-cols nibble mask ----------------
// m13 pattern: lane-contiguous float4, grid-stride, 32 waves/CU.
// adj values are exactly 0.0/1.0, so nibble = (int)(x + 2y + 4z + 8w).
__global__ __launch_bounds__(256) void k_mask(const float* __restrict__ adj,
                                              unsigned char* __restrict__ m8) {
  const int TOT = 2048 * 256;
  int tid = blockIdx.x * 256 + threadIdx.x;
#pragma unroll 4
  for (int p = 0; p < 32; ++p) {
    size_t w = (size_t)p * TOT + tid;      // float4 index; lanes contiguous
    float4 v = *reinterpret_cast<const float4*>(adj + w * 4);
    float bs = v.x + 2.f * v.y + 4.f * v.z + 8.f * v.w;
    m8[w] = (unsigned char)(int)bs;
  }
}

// ---------------- k0: Wt[f][k] = bf16(W[k][f]) ----------------
__global__ __launch_bounds__(256) void k0_wt(const float* __restrict__ W,
                                             unsigned short* __restrict__ Wt) {
  int k = blockIdx.x;
  int f = threadIdx.x;
  Wt[f * 256 + k] = f2bf(W[k * 256 + f]);
}

// ---------------- k1: WhbT[f][j] = bf16( (h@W)[j][f] ) ----------------
__global__ __launch_bounds__(256) void k1_wh(const float* __restrict__ h,
                                             const unsigned short* __restrict__ Wt,
                                             unsigned short* __restrict__ WhbT) {
  __shared__ char lds[8192 + 32768];
  char* Alds = lds;
  char* Blds = lds + 8192;
  int t = threadIdx.x;
  int i0 = blockIdx.x * 64;
  int l = t & 63, w = t >> 6;
  int lr = l & 15, lk = l >> 4;
  f32x4 acc[4][4] = {};
  for (int kt = 0; kt < 4; ++kt) {
    int k0 = kt * 64;
    if (kt) __syncthreads();
#pragma unroll
    for (int c = 0; c < 4; ++c) {
      int flat = c * 256 + t;
      int i = flat >> 4, jc = flat & 15;
      float4 v = *reinterpret_cast<const float4*>(h + (size_t)(i0 + i) * 256 + k0 + jc * 4);
      ushort4 pk;
      pk.x = f2bf(v.x); pk.y = f2bf(v.y); pk.z = f2bf(v.z); pk.w = f2bf(v.w);
      *reinterpret_cast<ushort4*>(Alds + i * 128 + ((jc * 8) ^ ((i & 7) << 4))) = pk;
    }
#pragma unroll
    for (int c = 0; c < 8; ++c) {
      int idx = c * 256 + t;
      int fr = idx >> 3, kc = idx & 7;
      uint4 v = *reinterpret_cast<const uint4*>(Wt + fr * 256 + k0 + kc * 8);
      *reinterpret_cast<uint4*>(Blds + fr * 128 + ((kc * 16) ^ ((fr & 7) << 4))) = v;
    }
    __syncthreads();
#pragma unroll
    for (int kk = 0; kk < 2; ++kk) {
      int kofs = kk * 64 + lk * 16;
      s16x8 afr[4], bfr[4];
#pragma unroll
      for (int mf = 0; mf < 4; ++mf) {
        int ar = mf * 16 + lr;
        afr[mf] = *reinterpret_cast<const s16x8*>(Alds + ar * 128 + (kofs ^ ((ar & 7) << 4)));
      }
#pragma unroll
      for (int nf = 0; nf < 4; ++nf) {
        int br = w * 64 + nf * 16 + lr;
        bfr[nf] = *reinterpret_cast<const s16x8*>(Blds + br * 128 + (kofs ^ ((br & 7) << 4)));
      }
#pragma unroll
      for (int mf = 0; mf < 4; ++mf)
#pragma unroll
        for (int nf = 0; nf < 4; ++nf)
          acc[mf][nf] = __builtin_amdgcn_mfma_f32_16x16x32_bf16(afr[mf], bfr[nf], acc[mf][nf], 0, 0, 0);
    }
  }
#pragma unroll
  for (int mf = 0; mf < 4; ++mf) {
#pragma unroll
    for (int nf = 0; nf < 4; ++nf) {
      int f = w * 64 + nf * 16 + lr;
      int j = i0 + mf * 16 + lk * 4;
      ushort4 pk;
      pk.x = f2bf(acc[mf][nf][0]);
      pk.y = f2bf(acc[mf][nf][1]);
      pk.z = f2bf(acc[mf][nf][2]);
      pk.w = f2bf(acc[mf][nf][3]);
      *reinterpret_cast<ushort4*>(WhbT + (size_t)f * N + j) = pk;
    }
  }
}

// ---------------- k2: s1/s2 ----------------
__global__ __launch_bounds__(256) void k2_s(const unsigned short* __restrict__ WhbT,
                                            const float* __restrict__ a,
                                            float* __restrict__ s1,
                                            float* __restrict__ s2) {
  int j = blockIdx.x * 256 + threadIdx.x;
  float acc1 = 0.f, acc2 = 0.f;
#pragma unroll 8
  for (int f = 0; f < 256; ++f) {
    float v = bf2f(WhbT[(size_t)f * N + j]);
    acc1 += v * a[f];
    acc2 += v * a[256 + f];
  }
  s1[j] = acc1;
  s2[j] = acc2;
}

// ---------------- k3: masked-softmax-weighted GEMM, mask via reg prefetch ----------------
__global__ __launch_bounds__(512) void k3_attn(const unsigned char* __restrict__ m8,
                                               const unsigned short* __restrict__ WhbT,
                                               const float* __restrict__ s1,
                                               const float* __restrict__ s2,
                                               float* __restrict__ numw,
                                               float* __restrict__ denw) {
  __shared__ char lds[32768 + 65536 + 512];
  char* Abuf = lds;               // 2 x 16KB P tiles
  char* Bbuf = lds + 32768;       // 2 x 32KB Wh tiles
  float* denl = (float*)(lds + 98304);
  int t = threadIdx.x;
  int i0 = blockIdx.x * 128;
  int jb = blockIdx.y * JB;
  int l = t & 63, w = t >> 6, wm = w >> 2, wn = w & 3;
  int lr = l & 15, lk = l >> 4;
  int g = t >> 4;
  int jl = (t & 15) * 4;

  // per-lane mask byte base: row (i0 + c*32 + g), byte col (jb>>2) + (t&15)
  const unsigned char* mbase[4];
#pragma unroll
  for (int c = 0; c < 4; ++c)
    mbase[c] = m8 + (size_t)(i0 + c * 32 + g) * (N / 4) + (jb >> 2) + (t & 15);

  unsigned int mcur[4];
#pragma unroll
  for (int c = 0; c < 4; ++c) mcur[c] = mbase[c][0];   // tile 0

  float s1v[4];
#pragma unroll
  for (int c = 0; c < 4; ++c) s1v[c] = s1[i0 + c * 32 + g];

  float dsum[4] = {0.f, 0.f, 0.f, 0.f};
  f32x4 acc[4][4] = {};

  auto stage = [&](int nt, int nb) {
    int j0 = jb + nt * 64;
    uint4 bv[4];
#pragma unroll
    for (int c = 0; c < 4; ++c) {
      int idx = c * 512 + t;
      int fr = idx >> 3, kc = idx & 7;
      bv[c] = *reinterpret_cast<const uint4*>(WhbT + (size_t)fr * N + j0 + kc * 8);
    }
    float4 s2v = *reinterpret_cast<const float4*>(s2 + j0 + jl);
    char* A = Abuf + nb * 16384;
#pragma unroll
    for (int c = 0; c < 4; ++c) {
      int i = c * 32 + g;
      unsigned int nib = mcur[c] & 0xFu;
      float s1c = s1v[c];
      float x, p0, p1, p2, p3;
      x = s1c + s2v.x; x = fmaxf(x, 0.2f * x); p0 = (nib & 1u) ? __expf(x) : 0.f;
      x = s1c + s2v.y; x = fmaxf(x, 0.2f * x); p1 = (nib & 2u) ? __expf(x) : 0.f;
      x = s1c + s2v.z; x = fmaxf(x, 0.2f * x); p2 = (nib & 4u) ? __expf(x) : 0.f;
      x = s1c + s2v.w; x = fmaxf(x, 0.2f * x); p3 = (nib & 8u) ? __expf(x) : 0.f;
      ushort4 pk;
      pk.x = f2bf(p0); pk.y = f2bf(p1); pk.z = f2bf(p2); pk.w = f2bf(p3);
      dsum[c] += bf2f(pk.x) + bf2f(pk.y) + bf2f(pk.z) + bf2f(pk.w);
      *reinterpret_cast<ushort4*>(A + i * 128 + ((jl * 2) ^ ((i & 7) << 4))) = pk;
    }
    // prefetch next tile's mask bytes (full MFMA+barrier of latency cover)
    int np = (nt + 1 < NIT) ? nt + 1 : nt;
#pragma unroll
    for (int c = 0; c < 4; ++c) mcur[c] = mbase[c][np * 16];
    char* B = Bbuf + nb * 32768;
#pragma unroll
    for (int c = 0; c < 4; ++c) {
      int idx = c * 512 + t;
      int fr = idx >> 3, kc = idx & 7;
      *reinterpret_cast<uint4*>(B + fr * 128 + ((kc * 16) ^ ((fr & 7) << 4))) = bv[c];
    }
  };

  stage(0, 0);
  __syncthreads();

  for (int it = 0; it < NIT; ++it) {
    int cb = it & 1;
    if (it + 1 < NIT) stage(it + 1, cb ^ 1);
    char* A = Abuf + cb * 16384;
    char* B = Bbuf + cb * 32768;
#pragma unroll
    for (int kk = 0; kk < 2; ++kk) {
      int kofs = kk * 64 + lk * 16;
      s16x8 afr[4], bfr[4];
#pragma unroll
      for (int mf = 0; mf < 4; ++mf) {
        int ar = wm * 64 + mf * 16 + lr;
        afr[mf] = *reinterpret_cast<const s16x8*>(A + ar * 128 + (kofs ^ ((ar & 7) << 4)));
      }
#pragma unroll
      for (int nf = 0; nf < 4; ++nf) {
        int br = wn * 64 + nf * 16 + lr;
        bfr[nf] = *reinterpret_cast<const s16x8*>(B + br * 128 + (kofs ^ ((br & 7) << 4)));
      }
#pragma unroll
      for (int mf = 0; mf < 4; ++mf)
#pragma unroll
        for (int nf = 0; nf < 4; ++nf)
          acc[mf][nf] = __builtin_amdgcn_mfma_f32_16x16x32_bf16(afr[mf], bfr[nf], acc[mf][nf], 0, 0, 0);
    }
    __syncthreads();
  }

#pragma unroll
  for (int c = 0; c < 4; ++c) {
    float v = dsum[c];
    v += __shfl_xor(v, 1);
    v += __shfl_xor(v, 2);
    v += __shfl_xor(v, 4);
    v += __shfl_xor(v, 8);
    if ((t & 15) == 0) denl[c * 32 + g] = v;
  }
  __syncthreads();
  float* nump = numw + (size_t)blockIdx.y * N * F;
#pragma unroll
  for (int mf = 0; mf < 4; ++mf) {
#pragma unroll
    for (int nf = 0; nf < 4; ++nf) {
      int f = wn * 64 + nf * 16 + lr;
      int irow = i0 + wm * 64 + mf * 16 + lk * 4;
#pragma unroll
      for (int r = 0; r < 4; ++r)
        nump[(size_t)(irow + r) * F + f] = acc[mf][nf][r];
    }
  }
  if (t < 128) denw[(size_t)blockIdx.y * N + i0 + t] = denl[t];
}

// ---------------- k4: combine K-splits, divide, elu (float4) ----------------
__global__ __launch_bounds__(256) void k4_fin(const float* __restrict__ numw,
                                              const float* __restrict__ denw,
                                              float* __restrict__ out) {
  int idx = (blockIdx.x * 256 + threadIdx.x) * 4;
  int i = idx >> 8;
  float4 sn = {0.f, 0.f, 0.f, 0.f};
  float sd = 0.f;
#pragma unroll
  for (int ksp = 0; ksp < KSPLIT; ++ksp) {
    float4 v = *reinterpret_cast<const float4*>(numw + (size_t)ksp * N * F + idx);
    sn.x += v.x; sn.y += v.y; sn.z += v.z; sn.w += v.w;
    sd += denw[ksp * N + i];
  }
  float r = 1.f / sd;
  float4 o;
  float hp;
  hp = sn.x * r; o.x = hp > 0.f ? hp : (__expf(hp) - 1.f);
  hp = sn.y * r; o.y = hp > 0.f ? hp : (__expf(hp) - 1.f);
  hp = sn.z * r; o.z = hp > 0.f ? hp : (__expf(hp) - 1.f);
  hp = sn.w * r; o.w = hp > 0.f ? hp : (__expf(hp) - 1.f);
  *reinterpret_cast<float4*>(out + idx) = o;
}

extern "C" void kernel_launch(void* const* d_in, const int* in_sizes, int n_in,
                              void* d_out, int out_size, void* d_ws, size_t ws_size,
                              hipStream_t stream) {
  const float* h   = (const float*)d_in[0];
  const float* adj = (const float*)d_in[1];
  const float* W   = (const float*)d_in[2];
  const float* a   = (const float*)d_in[3];
  float* out = (float*)d_out;

  char* ws = (char*)d_ws;
  size_t o = 0;
  unsigned short* WhbT = (unsigned short*)(ws + o); o += (size_t)4 * 1024 * 1024;
  float* s1            = (float*)(ws + o); o += 32768;
  float* s2            = (float*)(ws + o); o += 32768;
  float* denw          = (float*)(ws + o); o += 131072;
  unsigned short* Wt   = (unsigned short*)(ws + o); o += 131072;
  float* numw          = (float*)(ws + o); o += (size_t)KSPLIT * N * F * 4;   // 32 MB
  unsigned char* m8    = (unsigned char*)(ws + o); o += (size_t)N * (N / 4) + 256; // 16 MB

  hipLaunchKernelGGL(k_mask, dim3(2048), dim3(256), 0, stream, adj, m8);
  hipLaunchKernelGGL(k0_wt, dim3(256), dim3(256), 0, stream, W, Wt);
  hipLaunchKernelGGL(k1_wh, dim3(N / 64), dim3(256), 0, stream, h, Wt, WhbT);
  hipLaunchKernelGGL(k2_s, dim3(N / 256), dim3(256), 0, stream, WhbT, a, s1, s2);
  hipLaunchKernelGGL(k3_attn, dim3(64, KSPLIT), dim3(512), 0, stream,
                     m8, WhbT, s1, s2, numw, denw);
  hipLaunchKernelGGL(k4_fin, dim3(N * F / 1024), dim3(256), 0, stream, numw, denw, out);
}

// Round 5
// 146.838 us; speedup vs baseline: 1.2466x; 1.2466x over previous
//
#include <hip/hip_runtime.h>
#include <hip/hip_bf16.h>

#define N 8192
#define F 256
#define KSPLIT 4
#define JBLK (N / KSPLIT)    // 2048 cols per k3 block
#define NITER (JBLK / 64)    // 32 j-tiles of 64

using s16x8 = __attribute__((ext_vector_type(8))) short;
using f32x4 = __attribute__((ext_vector_type(4))) float;

static __device__ __forceinline__ unsigned short f2bf(float f) {
  unsigned int u = __float_as_uint(f);
  unsigned int r = u + 0x7fffu + ((u >> 16) & 1u);   // RNE
  return (unsigned short)(r >> 16);
}
static __device__ __forceinline__ float bf2f(unsigned short u) {
  return __uint_as_float(((unsigned int)u) << 16);
}

// ---------------- k0: Wt[f][k] = bf16(W[k][f]) ----------------
__global__ __launch_bounds__(256) void k0_wt(const float* __restrict__ W,
                                             unsigned short* __restrict__ Wt) {
  int k = blockIdx.x;
  int f = threadIdx.x;
  Wt[f * 256 + k] = f2bf(W[k * 256 + f]);
}

// ---------------- k1: WhbT[f][j] = bf16( (h@W)[j][f] ) ----------------
__global__ __launch_bounds__(256) void k1_wh(const float* __restrict__ h,
                                             const unsigned short* __restrict__ Wt,
                                             unsigned short* __restrict__ WhbT) {
  __shared__ char lds[8192 + 32768];
  char* Alds = lds;
  char* Blds = lds + 8192;
  int t = threadIdx.x;
  int i0 = blockIdx.x * 64;
  int l = t & 63, w = t >> 6;
  int lr = l & 15, lk = l >> 4;
  f32x4 acc[4][4] = {};
  for (int kt = 0; kt < 4; ++kt) {
    int k0 = kt * 64;
    if (kt) __syncthreads();
#pragma unroll
    for (int c = 0; c < 4; ++c) {
      int flat = c * 256 + t;
      int i = flat >> 4, jc = flat & 15;
      float4 v = *reinterpret_cast<const float4*>(h + (size_t)(i0 + i) * 256 + k0 + jc * 4);
      ushort4 pk;
      pk.x = f2bf(v.x); pk.y = f2bf(v.y); pk.z = f2bf(v.z); pk.w = f2bf(v.w);
      *reinterpret_cast<ushort4*>(Alds + i * 128 + ((jc * 8) ^ ((i & 7) << 4))) = pk;
    }
#pragma unroll
    for (int c = 0; c < 8; ++c) {
      int idx = c * 256 + t;
      int fr = idx >> 3, kc = idx & 7;
      uint4 v = *reinterpret_cast<const uint4*>(Wt + fr * 256 + k0 + kc * 8);
      *reinterpret_cast<uint4*>(Blds + fr * 128 + ((kc * 16) ^ ((fr & 7) << 4))) = v;
    }
    __syncthreads();
#pragma unroll
    for (int kk = 0; kk < 2; ++kk) {
      int kofs = kk * 64 + lk * 16;
      s16x8 afr[4], bfr[4];
#pragma unroll
      for (int mf = 0; mf < 4; ++mf) {
        int ar = mf * 16 + lr;
        afr[mf] = *reinterpret_cast<const s16x8*>(Alds + ar * 128 + (kofs ^ ((ar & 7) << 4)));
      }
#pragma unroll
      for (int nf = 0; nf < 4; ++nf) {
        int br = w * 64 + nf * 16 + lr;
        bfr[nf] = *reinterpret_cast<const s16x8*>(Blds + br * 128 + (kofs ^ ((br & 7) << 4)));
      }
#pragma unroll
      for (int mf = 0; mf < 4; ++mf)
#pragma unroll
        for (int nf = 0; nf < 4; ++nf)
          acc[mf][nf] = __builtin_amdgcn_mfma_f32_16x16x32_bf16(afr[mf], bfr[nf], acc[mf][nf], 0, 0, 0);
    }
  }
#pragma unroll
  for (int mf = 0; mf < 4; ++mf) {
#pragma unroll
    for (int nf = 0; nf < 4; ++nf) {
      int f = w * 64 + nf * 16 + lr;
      int j = i0 + mf * 16 + lk * 4;
      ushort4 pk;
      pk.x = f2bf(acc[mf][nf][0]);
      pk.y = f2bf(acc[mf][nf][1]);
      pk.z = f2bf(acc[mf][nf][2]);
      pk.w = f2bf(acc[mf][nf][3]);
      *reinterpret_cast<ushort4*>(WhbT + (size_t)f * N + j) = pk;
    }
  }
}

// ---------------- k2: s1/s2 ----------------
__global__ __launch_bounds__(256) void k2_s(const unsigned short* __restrict__ WhbT,
                                            const float* __restrict__ a,
                                            float* __restrict__ s1,
                                            float* __restrict__ s2) {
  int j = blockIdx.x * 256 + threadIdx.x;
  float acc1 = 0.f, acc2 = 0.f;
#pragma unroll 8
  for (int f = 0; f < 256; ++f) {
    float v = bf2f(WhbT[(size_t)f * N + j]);
    acc1 += v * a[f];
    acc2 += v * a[256 + f];
  }
  s1[j] = acc1;
  s2[j] = acc2;
}

// ---------------- k3: fused adj->P(regs)->MFMA, no A-LDS, B double-buffered ----------------
// 256 thr (4 waves x 16 rows), M=64/block, grid (128, KSPLIT) = 512 blocks = 2/CU.
// Lane (lr,lk) owns adj row i0+wv*16+lr, j-slice lk*8..lk*8+7 of each 64-tile —
// exactly the MFMA A-fragment layout, so P never touches LDS.
__global__ __launch_bounds__(256, 2) void k3_attn(const float* __restrict__ adj,
                                                  const unsigned short* __restrict__ WhbT,
                                                  const float* __restrict__ s1,
                                                  const float* __restrict__ s2,
                                                  float* __restrict__ numw,
                                                  float* __restrict__ denw) {
  __shared__ char Bbuf[2 * 32768];   // 2 x (256 f-rows x 128 B)
  int t = threadIdx.x;
  int wv = t >> 6;
  int l = t & 63;
  int lr = l & 15, lk = l >> 4;
  int i0 = blockIdx.x * 64;
  int ks = blockIdx.y;
  int jb = ks * JBLK;
  int row = i0 + wv * 16 + lr;
  const float* arow = adj + (size_t)row * N + jb;
  const float* s2b = s2 + jb;
  float s1v = s1[row];
  int lko = lk * 8;

  f32x4 acc[16] = {};
  float dsum = 0.f;

  float4 ajc[4], svc[4], ajn[4], svn[4];   // [kk*2+h]
  uint4 bvn[8];

  // ---- prologue: adj/s2 tile 0 -> regs, B tile 0 -> LDS ----
#pragma unroll
  for (int kk = 0; kk < 2; ++kk)
#pragma unroll
    for (int h = 0; h < 2; ++h) {
      ajc[kk * 2 + h] = *reinterpret_cast<const float4*>(arow + kk * 32 + lko + h * 4);
      svc[kk * 2 + h] = *reinterpret_cast<const float4*>(s2b + kk * 32 + lko + h * 4);
    }
#pragma unroll
  for (int c = 0; c < 8; ++c) {
    int idx = c * 256 + t;
    int fr = idx >> 3, kc = idx & 7;
    bvn[c] = *reinterpret_cast<const uint4*>(WhbT + (size_t)fr * N + jb + kc * 8);
  }
#pragma unroll
  for (int c = 0; c < 8; ++c) {
    int idx = c * 256 + t;
    int fr = idx >> 3, kc = idx & 7;
    *reinterpret_cast<uint4*>(Bbuf + fr * 128 + ((kc * 16) ^ ((fr & 7) << 4))) = bvn[c];
  }
  __syncthreads();

  for (int it = 0; it < NITER; ++it) {
    bool pf = (it + 1 < NITER);
    // ---- issue next-tile loads (adj first: longest latency) ----
    if (pf) {
      int jn = (it + 1) * 64;
#pragma unroll
      for (int kk = 0; kk < 2; ++kk)
#pragma unroll
        for (int h = 0; h < 2; ++h)
          ajn[kk * 2 + h] = *reinterpret_cast<const float4*>(arow + jn + kk * 32 + lko + h * 4);
#pragma unroll
      for (int c = 0; c < 8; ++c) {
        int idx = c * 256 + t;
        int fr = idx >> 3, kc = idx & 7;
        bvn[c] = *reinterpret_cast<const uint4*>(WhbT + (size_t)fr * N + jb + jn + kc * 8);
      }
#pragma unroll
      for (int kk = 0; kk < 2; ++kk)
#pragma unroll
        for (int h = 0; h < 2; ++h)
          svn[kk * 2 + h] = *reinterpret_cast<const float4*>(s2b + jn + kk * 32 + lko + h * 4);
    }
    // ---- P compute (registers only) ----
    s16x8 afr[2];
#pragma unroll
    for (int kk = 0; kk < 2; ++kk) {
      unsigned short u[8];
#pragma unroll
      for (int h = 0; h < 2; ++h) {
        float4 av = ajc[kk * 2 + h];
        float4 tv = svc[kk * 2 + h];
        float x;
        x = s1v + tv.x; x = fmaxf(x, 0.2f * x); u[h * 4 + 0] = av.x > 0.f ? f2bf(__expf(x)) : 0;
        x = s1v + tv.y; x = fmaxf(x, 0.2f * x); u[h * 4 + 1] = av.y > 0.f ? f2bf(__expf(x)) : 0;
        x = s1v + tv.z; x = fmaxf(x, 0.2f * x); u[h * 4 + 2] = av.z > 0.f ? f2bf(__expf(x)) : 0;
        x = s1v + tv.w; x = fmaxf(x, 0.2f * x); u[h * 4 + 3] = av.w > 0.f ? f2bf(__expf(x)) : 0;
      }
      s16x8 af;
#pragma unroll
      for (int e = 0; e < 8; ++e) {
        af[e] = (short)u[e];
        dsum += bf2f(u[e]);
      }
      afr[kk] = af;
    }
    // ---- MFMA on current B buffer ----
    const char* B = Bbuf + (it & 1) * 32768;
#pragma unroll
    for (int kk = 0; kk < 2; ++kk) {
      int kofs = kk * 64 + lk * 16;
#pragma unroll
      for (int nf = 0; nf < 16; ++nf) {
        int br = nf * 16 + lr;
        s16x8 bfr = *reinterpret_cast<const s16x8*>(B + br * 128 + (kofs ^ ((br & 7) << 4)));
        acc[nf] = __builtin_amdgcn_mfma_f32_16x16x32_bf16(afr[kk], bfr, acc[nf], 0, 0, 0);
      }
    }
    // ---- write next B tile into other buffer ----
    if (pf) {
      char* B1 = Bbuf + ((it + 1) & 1) * 32768;
#pragma unroll
      for (int c = 0; c < 8; ++c) {
        int idx = c * 256 + t;
        int fr = idx >> 3, kc = idx & 7;
        *reinterpret_cast<uint4*>(B1 + fr * 128 + ((kc * 16) ^ ((fr & 7) << 4))) = bvn[c];
      }
    }
    __syncthreads();
    if (pf) {
#pragma unroll
      for (int q = 0; q < 4; ++q) { ajc[q] = ajn[q]; svc[q] = svn[q]; }
    }
  }

  // ---- denominator: reduce over lk groups (j-partitions) ----
  dsum += __shfl_xor(dsum, 16);
  dsum += __shfl_xor(dsum, 32);
  if (l < 16) denw[(size_t)ks * N + row] = dsum;

  // ---- numerator partials ----
  float* nump = numw + (size_t)ks * N * F;
#pragma unroll
  for (int nf = 0; nf < 16; ++nf) {
#pragma unroll
    for (int r = 0; r < 4; ++r) {
      nump[(size_t)(i0 + wv * 16 + lk * 4 + r) * F + nf * 16 + lr] = acc[nf][r];
    }
  }
}

// ---------------- k4: combine K-splits, divide, elu (float4) ----------------
__global__ __launch_bounds__(256) void k4_fin(const float* __restrict__ numw,
                                              const float* __restrict__ denw,
                                              float* __restrict__ out) {
  int idx = (blockIdx.x * 256 + threadIdx.x) * 4;
  int i = idx >> 8;
  float4 sn = {0.f, 0.f, 0.f, 0.f};
  float sd = 0.f;
#pragma unroll
  for (int ksp = 0; ksp < KSPLIT; ++ksp) {
    float4 v = *reinterpret_cast<const float4*>(numw + (size_t)ksp * N * F + idx);
    sn.x += v.x; sn.y += v.y; sn.z += v.z; sn.w += v.w;
    sd += denw[ksp * N + i];
  }
  float r = 1.f / sd;
  float4 o;
  float hp;
  hp = sn.x * r; o.x = hp > 0.f ? hp : (__expf(hp) - 1.f);
  hp = sn.y * r; o.y = hp > 0.f ? hp : (__expf(hp) - 1.f);
  hp = sn.z * r; o.z = hp > 0.f ? hp : (__expf(hp) - 1.f);
  hp = sn.w * r; o.w = hp > 0.f ? hp : (__expf(hp) - 1.f);
  *reinterpret_cast<float4*>(out + idx) = o;
}

extern "C" void kernel_launch(void* const* d_in, const int* in_sizes, int n_in,
                              void* d_out, int out_size, void* d_ws, size_t ws_size,
                              hipStream_t stream) {
  const float* h   = (const float*)d_in[0];
  const float* adj = (const float*)d_in[1];
  const float* W   = (const float*)d_in[2];
  const float* a   = (const float*)d_in[3];
  float* out = (float*)d_out;

  char* ws = (char*)d_ws;
  size_t o = 0;
  unsigned short* WhbT = (unsigned short*)(ws + o); o += (size_t)4 * 1024 * 1024;
  float* s1            = (float*)(ws + o); o += 32768;
  float* s2            = (float*)(ws + o); o += 32768;
  float* denw          = (float*)(ws + o); o += 131072;
  unsigned short* Wt   = (unsigned short*)(ws + o); o += 131072;
  float* numw          = (float*)(ws + o); o += (size_t)KSPLIT * N * F * 4;   // 32 MB

  hipLaunchKernelGGL(k0_wt, dim3(256), dim3(256), 0, stream, W, Wt);
  hipLaunchKernelGGL(k1_wh, dim3(N / 64), dim3(256), 0, stream, h, Wt, WhbT);
  hipLaunchKernelGGL(k2_s, dim3(N / 256), dim3(256), 0, stream, WhbT, a, s1, s2);
  hipLaunchKernelGGL(k3_attn, dim3(128, KSPLIT), dim3(256), 0, stream,
                     adj, WhbT, s1, s2, numw, denw);
  hipLaunchKernelGGL(k4_fin, dim3(N * F / 1024), dim3(256), 0, stream, numw, denw, out);
}